// Round 1
// baseline (321.231 us; speedup 1.0000x reference)
//
#include <hip/hip_runtime.h>

typedef unsigned short u16;
typedef __attribute__((ext_vector_type(8))) short bf16x8;   // 8 bf16 in 4 VGPRs
typedef __attribute__((ext_vector_type(4))) float floatx4;

__device__ __forceinline__ u16 f2b(float f) {
    union { float f; unsigned u; } v; v.f = f;
    return (u16)((v.u + 0x7FFFu + ((v.u >> 16) & 1u)) >> 16);   // RNE
}
__device__ __forceinline__ float b2f(u16 u) {
    union { unsigned u; float f; } v; v.u = ((unsigned)u) << 16;
    return v.f;
}

// ---------------- P0: weight prep (bf16 transposes) ----------------
// W2t[k][n][kk] (2,256,256); Wo1t[n][kk] (256,288 padded); Wo2t[n][kk] (256,256)
__global__ void prep_weights(const float* __restrict__ Wm2, const float* __restrict__ Wo1,
                             const float* __restrict__ Wo2,
                             u16* __restrict__ W2t, u16* __restrict__ Wo1t, u16* __restrict__ Wo2t) {
    int tid = blockIdx.x * blockDim.x + threadIdx.x;
    int stride = gridDim.x * blockDim.x;
    for (int idx = tid; idx < 2 * 256 * 256; idx += stride) {
        int k = idx >> 16, rem = idx & 65535, n = rem >> 8, kk = rem & 255;
        W2t[idx] = f2b(Wm2[(k * 256 + kk) * 256 + n]);
    }
    for (int idx = tid; idx < 256 * 288; idx += stride) {
        int n = idx / 288, kk = idx % 288;
        Wo1t[idx] = f2b(kk < 280 ? Wo1[kk * 256 + n] : 0.f);
    }
    for (int idx = tid; idx < 256 * 256; idx += stride) {
        int n = idx >> 8, kk = idx & 255;
        Wo2t[idx] = f2b(Wo2[kk * 256 + n]);
    }
}

// ---------------- P1: x0 + u1/u2 (layer-1 factorization) ----------------
// u1[b,n,k,h] = x0[b,n]·W1[k][0:24,h]     (sender part)
// u2[b,n,k,h] = x0[b,n]·W1[k][24:48,h]+b1 (receiver part, bias folded)
__global__ void compute_u(const float* __restrict__ data, const float* __restrict__ act,
                          const float* __restrict__ Wm1, const float* __restrict__ bm1,
                          float* __restrict__ x0, u16* __restrict__ u1, u16* __restrict__ u2) {
    int r0 = blockIdx.x * 16;   // 16 (b,n) rows per block, 256 blocks
    __shared__ float xs[16][24];
    int tid = threadIdx.x;
    for (int idx = tid; idx < 16 * 24; idx += 256) {
        int rr = idx / 24, d = idx % 24;
        int r = r0 + rr;
        float v = (d < 16) ? data[(r * 2 + 0) * 16 + d]       // t=0
                           : act[(r * 2 + 0) * 8 + (d - 16)];
        xs[rr][d] = v;
        x0[r * 24 + d] = v;
    }
    __syncthreads();
    int h = tid;
    float acc[4][16];
#pragma unroll
    for (int q = 0; q < 4; q++)
#pragma unroll
        for (int rr = 0; rr < 16; rr++) acc[q][rr] = 0.f;
#pragma unroll
    for (int d = 0; d < 24; d++) {
        float w10 = Wm1[(0 * 48 + d) * 256 + h];
        float w11 = Wm1[(1 * 48 + d) * 256 + h];
        float w20 = Wm1[(0 * 48 + 24 + d) * 256 + h];
        float w21 = Wm1[(1 * 48 + 24 + d) * 256 + h];
#pragma unroll
        for (int rr = 0; rr < 16; rr++) {
            float x = xs[rr][d];
            acc[0][rr] += x * w10;
            acc[1][rr] += x * w11;
            acc[2][rr] += x * w20;
            acc[3][rr] += x * w21;
        }
    }
    float bb0 = bm1[h], bb1 = bm1[256 + h];
#pragma unroll
    for (int rr = 0; rr < 16; rr++) {
        int r = r0 + rr;
        u1[(r * 2 + 0) * 256 + h] = f2b(acc[0][rr]);
        u1[(r * 2 + 1) * 256 + h] = f2b(acc[1][rr]);
        u2[(r * 2 + 0) * 256 + h] = f2b(acc[2][rr] + bb0);
        u2[(r * 2 + 1) * 256 + h] = f2b(acc[3][rr] + bb1);
    }
}

__global__ void init_out(const float* __restrict__ bq3, float* __restrict__ out) {
    if (threadIdx.x < 64) out[threadIdx.x] = bq3[0];
}

// ---------------- K3: fused edge MLP layer-2 + weighted aggregate ----------------
// block = (b,i): rows j=0..63 (senders, j=i padded w/ weight 0); computes
// agg[b,i,:] = sum_j sum_k relu( relu(u1[b,j,k]+u2[b,i,k]) @ W2[k] + b2[k] ) * edge[b,e(j,i),k]
#define AS_STRIDE 264   // 256+8 (528B rows, 16B aligned, 2-way-max bank alias)
#define BS_STRIDE 40    // 32+8  (80B rows,  16B aligned)
__global__ __launch_bounds__(256, 2) void edge_kernel(
    const u16* __restrict__ u1, const u16* __restrict__ u2, const float* __restrict__ edges,
    const u16* __restrict__ W2t, const float* __restrict__ bm2, float* __restrict__ agg) {
    int blk = blockIdx.x;
    int b = blk >> 6, i = blk & 63;
    __shared__ __align__(16) u16 As[64 * AS_STRIDE];
    __shared__ __align__(16) u16 Bs[256 * BS_STRIDE];
    __shared__ float agg_s[256];
    __shared__ float w_s[64];
    __shared__ float b2_s[256];
    int tid = threadIdx.x;
    int lane = tid & 63, wave = tid >> 6;
    agg_s[tid] = 0.f;                    // wave w inits exactly its own col range
    const int colBase = wave * 64;
    const int mrow = lane & 15;
    const int k8 = (lane >> 4) * 8;
    const int lhi = lane >> 4;

    for (int k = 0; k < 2; k++) {
        __syncthreads();                 // all waves done with As/w_s/b2_s of prev k
        if (tid < 64) {
            int j = tid;
            float w = 0.f;
            if (j != i) {
                int jj = j - (j > i ? 1 : 0);
                w = edges[(b * 4032 + i * 63 + jj) * 2 + k];
            }
            w_s[j] = w;
        }
        b2_s[tid] = bm2[k * 256 + tid];
        // stage A = relu(u1[b,j,k,:] + u2[b,i,k,:]) as bf16, 64x256
        {
            const u16* u2row = u2 + (((size_t)b * 64 + i) * 2 + k) * 256;
#pragma unroll
            for (int it = 0; it < 8; it++) {
                int chunk = tid + 256 * it;
                int j = chunk >> 5;
                int c0 = (chunk & 31) * 8;
                uint4 v1 = *(const uint4*)(u1 + (((size_t)b * 64 + j) * 2 + k) * 256 + c0);
                uint4 v2 = *(const uint4*)(u2row + c0);
                const u16* s1 = (const u16*)&v1;
                const u16* s2 = (const u16*)&v2;
                u16 o[8];
#pragma unroll
                for (int q = 0; q < 8; q++)
                    o[q] = f2b(fmaxf(b2f(s1[q]) + b2f(s2[q]), 0.f));
                *(uint4*)(&As[j * AS_STRIDE + c0]) = *(const uint4*)o;
            }
        }
        floatx4 acc[4][4];
#pragma unroll
        for (int rt = 0; rt < 4; rt++)
#pragma unroll
            for (int ct = 0; ct < 4; ct++)
#pragma unroll
                for (int q = 0; q < 4; q++) acc[rt][ct][q] = 0.f;

        for (int step = 0; step < 8; step++) {
            int kk0 = step * 32;
            __syncthreads();             // prev MFMA done with Bs; A visible on step 0
#pragma unroll
            for (int it = 0; it < 4; it++) {   // stage W2t[k][n][kk0:kk0+32] (transposed in prep)
                int chunk = tid + 256 * it;
                int n = chunk >> 2;
                int c0 = (chunk & 3) * 8;
                uint4 v = *(const uint4*)(W2t + ((size_t)(k * 256 + n)) * 256 + kk0 + c0);
                *(uint4*)(&Bs[n * BS_STRIDE + c0]) = v;
            }
            __syncthreads();
            bf16x8 af[4], bfr[4];
#pragma unroll
            for (int rt = 0; rt < 4; rt++)
                af[rt] = *(const bf16x8*)(&As[(rt * 16 + mrow) * AS_STRIDE + kk0 + k8]);
#pragma unroll
            for (int ct = 0; ct < 4; ct++)
                bfr[ct] = *(const bf16x8*)(&Bs[(colBase + ct * 16 + mrow) * BS_STRIDE + k8]);
#pragma unroll
            for (int rt = 0; rt < 4; rt++)
#pragma unroll
                for (int ct = 0; ct < 4; ct++)
                    acc[rt][ct] = __builtin_amdgcn_mfma_f32_16x16x32_bf16(
                        af[rt], bfr[ct], acc[rt][ct], 0, 0, 0);
        }
        // epilogue: relu(C+b2)*w, reduce over rows (C layout: col=lane&15, row=quad*4+reg)
#pragma unroll
        for (int ct = 0; ct < 4; ct++) {
            int col = colBase + ct * 16 + (lane & 15);
            float bb = b2_s[col];
            float p = 0.f;
#pragma unroll
            for (int rt = 0; rt < 4; rt++)
#pragma unroll
                for (int reg = 0; reg < 4; reg++) {
                    int row = rt * 16 + lhi * 4 + reg;
                    p += fmaxf(acc[rt][ct][reg] + bb, 0.f) * w_s[row];
                }
            p += __shfl_xor(p, 16, 64);
            p += __shfl_xor(p, 32, 64);
            if (lhi == 0) agg_s[col] += p;   // wave-private col range: no race
        }
    }
    __syncthreads();
    agg[(size_t)blk * 256 + tid] = agg_s[tid];
}

// ---------------- K4: out-MLP (280->256->256->24) + residual + q + final reduce ----------------
__global__ void out_mlp(const float* __restrict__ x0, const float* __restrict__ agg,
                        const u16* __restrict__ Wo1t, const u16* __restrict__ Wo2t,
                        const float* __restrict__ bo1, const float* __restrict__ bo2,
                        const float* __restrict__ Wo3, const float* __restrict__ bo3,
                        const float* __restrict__ Wq2, const float* __restrict__ bq2,
                        const float* __restrict__ Wq3, float* __restrict__ out) {
    int r0 = blockIdx.x * 16;            // 16 rows (all same b since 16 | 64)
    int b = r0 >> 6, n0 = r0 & 63;
    int tid = threadIdx.x;
    int lane = tid & 63, wave = tid >> 6;
    __shared__ __align__(16) u16 A1s[16 * 296];   // aug rows, K padded to 288
    __shared__ __align__(16) u16 A2s[16 * 264];   // h1 bf16
    __shared__ __align__(16) u16 Bs[256 * 40];    // weight K-slices (BK=32)
    __shared__ float h2s[16 * 257];
    __shared__ float pq[16 * 24];
    __shared__ float qs[16];

    for (int idx = tid; idx < 16 * 288; idx += 256) {
        int rr = idx / 288, c = idx % 288;
        float v;
        if (c < 24)       v = x0[(r0 + rr) * 24 + c];
        else if (c < 280) v = agg[(size_t)(r0 + rr) * 256 + (c - 24)];
        else              v = 0.f;
        A1s[rr * 296 + c] = f2b(v);
    }
    const int colBase = wave * 64;
    const int mrow = lane & 15;
    const int k8 = (lane >> 4) * 8;
    const int lhi = lane >> 4;

    // layer 1: K=288, 9 steps of 32
    floatx4 acc[4];
#pragma unroll
    for (int ct = 0; ct < 4; ct++)
#pragma unroll
        for (int q = 0; q < 4; q++) acc[ct][q] = 0.f;
    for (int step = 0; step < 9; step++) {
        int kk0 = step * 32;
        __syncthreads();
#pragma unroll
        for (int it = 0; it < 4; it++) {
            int chunk = tid + 256 * it;
            int n = chunk >> 2, c0 = (chunk & 3) * 8;
            uint4 v = *(const uint4*)(Wo1t + n * 288 + kk0 + c0);
            *(uint4*)(&Bs[n * 40 + c0]) = v;
        }
        __syncthreads();
        bf16x8 af = *(const bf16x8*)(&A1s[mrow * 296 + kk0 + k8]);
#pragma unroll
        for (int ct = 0; ct < 4; ct++) {
            bf16x8 bfr = *(const bf16x8*)(&Bs[(colBase + ct * 16 + mrow) * 40 + k8]);
            acc[ct] = __builtin_amdgcn_mfma_f32_16x16x32_bf16(af, bfr, acc[ct], 0, 0, 0);
        }
    }
#pragma unroll
    for (int ct = 0; ct < 4; ct++) {     // h1 = relu(C+bo1) -> A2s (bf16)
        int col = colBase + ct * 16 + (lane & 15);
        float bb = bo1[col];
#pragma unroll
        for (int reg = 0; reg < 4; reg++) {
            int row = lhi * 4 + reg;
            A2s[row * 264 + col] = f2b(fmaxf(acc[ct][reg] + bb, 0.f));
        }
    }
    // layer 2: K=256, 8 steps of 32
    floatx4 acc2[4];
#pragma unroll
    for (int ct = 0; ct < 4; ct++)
#pragma unroll
        for (int q = 0; q < 4; q++) acc2[ct][q] = 0.f;
    for (int step = 0; step < 8; step++) {
        int kk0 = step * 32;
        __syncthreads();                 // protects Bs reuse + A2s visibility
#pragma unroll
        for (int it = 0; it < 4; it++) {
            int chunk = tid + 256 * it;
            int n = chunk >> 2, c0 = (chunk & 3) * 8;
            uint4 v = *(const uint4*)(Wo2t + n * 256 + kk0 + c0);
            *(uint4*)(&Bs[n * 40 + c0]) = v;
        }
        __syncthreads();
        bf16x8 af = *(const bf16x8*)(&A2s[mrow * 264 + kk0 + k8]);
#pragma unroll
        for (int ct = 0; ct < 4; ct++) {
            bf16x8 bfr = *(const bf16x8*)(&Bs[(colBase + ct * 16 + mrow) * 40 + k8]);
            acc2[ct] = __builtin_amdgcn_mfma_f32_16x16x32_bf16(af, bfr, acc2[ct], 0, 0, 0);
        }
    }
#pragma unroll
    for (int ct = 0; ct < 4; ct++) {     // h2 = relu(C+bo2) -> h2s (fp32)
        int col = colBase + ct * 16 + (lane & 15);
        float bb = bo2[col];
#pragma unroll
        for (int reg = 0; reg < 4; reg++) {
            int row = lhi * 4 + reg;
            h2s[row * 257 + col] = fmaxf(acc2[ct][reg] + bb, 0.f);
        }
    }
    __syncthreads();
    // layer 3 (fp32 vector) + residual + q contribution
    for (int idx = tid; idx < 16 * 24; idx += 256) {
        int rr = idx / 24, d = idx % 24;
        float p = bo3[d];
#pragma unroll 8
        for (int h = 0; h < 256; h++)
            p += h2s[rr * 257 + h] * Wo3[h * 24 + d];
        float val = x0[(r0 + rr) * 24 + d] + p;   // residual
        pq[idx] = val * Wq2[d];
    }
    __syncthreads();
    if (tid < 16) {
        float q = bq2[0];
#pragma unroll
        for (int d = 0; d < 24; d++) q += pq[tid * 24 + d];
        qs[tid] = q * Wq3[n0 + tid];
    }
    __syncthreads();
    if (tid == 0) {
        float s = 0.f;
#pragma unroll
        for (int rr = 0; rr < 16; rr++) s += qs[rr];
        atomicAdd(out + b, s);
    }
}

extern "C" void kernel_launch(void* const* d_in, const int* in_sizes, int n_in,
                              void* d_out, int out_size, void* d_ws, size_t ws_size,
                              hipStream_t stream) {
    const float* data = (const float*)d_in[0];
    const float* act  = (const float*)d_in[1];
    const float* edges = (const float*)d_in[2];
    // d_in[3] rel_rec, d_in[4] rel_send, d_in[5] prediction_steps: structure hardcoded (steps=1)
    const float* Wm1 = (const float*)d_in[6];
    const float* bm1 = (const float*)d_in[7];
    const float* Wm2 = (const float*)d_in[8];
    const float* bm2 = (const float*)d_in[9];
    const float* Wo1 = (const float*)d_in[10];
    const float* bo1 = (const float*)d_in[11];
    const float* Wo2 = (const float*)d_in[12];
    const float* bo2 = (const float*)d_in[13];
    const float* Wo3 = (const float*)d_in[14];
    const float* bo3 = (const float*)d_in[15];
    const float* Wq2 = (const float*)d_in[16];
    const float* bq2 = (const float*)d_in[17];
    const float* Wq3 = (const float*)d_in[18];
    const float* bq3 = (const float*)d_in[19];
    float* out = (float*)d_out;

    char* ws = (char*)d_ws;
    size_t off = 0;
    auto carve = [&](size_t bytes) -> void* {
        void* p = ws + off;
        off += (bytes + 255) & ~(size_t)255;
        return p;
    };
    u16*   u1   = (u16*)carve((size_t)64 * 64 * 2 * 256 * 2);   // 4 MB
    u16*   u2   = (u16*)carve((size_t)64 * 64 * 2 * 256 * 2);   // 4 MB
    float* x0   = (float*)carve((size_t)64 * 64 * 24 * 4);
    float* agg  = (float*)carve((size_t)64 * 64 * 256 * 4);     // 4 MB
    u16*   W2t  = (u16*)carve((size_t)2 * 256 * 256 * 2);
    u16*   Wo1t = (u16*)carve((size_t)256 * 288 * 2);
    u16*   Wo2t = (u16*)carve((size_t)256 * 256 * 2);

    prep_weights<<<dim3(256), dim3(256), 0, stream>>>(Wm2, Wo1, Wo2, W2t, Wo1t, Wo2t);
    compute_u<<<dim3(256), dim3(256), 0, stream>>>(data, act, Wm1, bm1, x0, u1, u2);
    init_out<<<dim3(1), dim3(64), 0, stream>>>(bq3, out);
    edge_kernel<<<dim3(4096), dim3(256), 0, stream>>>(u1, u2, edges, W2t, bm2, agg);
    out_mlp<<<dim3(256), dim3(256), 0, stream>>>(x0, agg, Wo1t, Wo2t, bo1, bo2, Wo3, bo3,
                                                 Wq2, bq2, Wq3, out);
}

// Round 2
// 212.150 us; speedup vs baseline: 1.5142x; 1.5142x over previous
//
#include <hip/hip_runtime.h>

typedef unsigned short u16;
typedef __attribute__((ext_vector_type(8))) short bf16x8;   // 8 bf16 in 4 VGPRs
typedef __attribute__((ext_vector_type(4))) float floatx4;

__device__ __forceinline__ u16 f2b(float f) {
    union { float f; unsigned u; } v; v.f = f;
    return (u16)((v.u + 0x7FFFu + ((v.u >> 16) & 1u)) >> 16);   // RNE
}
__device__ __forceinline__ float b2f(u16 u) {
    union { unsigned u; float f; } v; v.u = ((unsigned)u) << 16;
    return v.f;
}

// ---------------- P0: weight prep -> MFMA B-fragment tables (bf16) ----------------
// Fragment entry (frag, lane, j) supplies B[k = quad*8+j][n = ntile*16 + (lane&15)]
// W2f : [k2][s<8][nt<16][lane][8]   (K=256, N=256, per message-MLP k)
// Wo1f: [s<9][nt<16][lane][8]       (K=288 padded from 280, N=256)
// Wo2f: [s<8][nt<16][lane][8]       (K=256, N=256)
// Wo3f: [s<8][nt<2][lane][8]        (K=256, N=32 padded from 24)
__global__ void prep_weights(const float* __restrict__ Wm2, const float* __restrict__ Wo1,
                             const float* __restrict__ Wo2, const float* __restrict__ Wo3,
                             u16* __restrict__ W2f, u16* __restrict__ Wo1f,
                             u16* __restrict__ Wo2f, u16* __restrict__ Wo3f) {
    int tid = blockIdx.x * blockDim.x + threadIdx.x;
    int stride = gridDim.x * blockDim.x;
    for (int idx = tid; idx < 2 * 8 * 16 * 64 * 8; idx += stride) {
        int j = idx & 7, l = (idx >> 3) & 63, nt = (idx >> 9) & 15, s = (idx >> 13) & 7, k = idx >> 16;
        int n = nt * 16 + (l & 15);
        int kk = s * 32 + ((l >> 4) & 3) * 8 + j;
        W2f[idx] = f2b(Wm2[(k * 256 + kk) * 256 + n]);
    }
    for (int idx = tid; idx < 9 * 16 * 64 * 8; idx += stride) {
        int j = idx & 7, l = (idx >> 3) & 63, nt = (idx >> 9) & 15, s = idx >> 13;
        int n = nt * 16 + (l & 15);
        int kk = s * 32 + ((l >> 4) & 3) * 8 + j;
        Wo1f[idx] = f2b(kk < 280 ? Wo1[kk * 256 + n] : 0.f);
    }
    for (int idx = tid; idx < 8 * 16 * 64 * 8; idx += stride) {
        int j = idx & 7, l = (idx >> 3) & 63, nt = (idx >> 9) & 15, s = idx >> 13;
        int n = nt * 16 + (l & 15);
        int kk = s * 32 + ((l >> 4) & 3) * 8 + j;
        Wo2f[idx] = f2b(Wo2[kk * 256 + n]);
    }
    for (int idx = tid; idx < 8 * 2 * 64 * 8; idx += stride) {
        int j = idx & 7, l = (idx >> 3) & 63, nt = (idx >> 9) & 1, s = idx >> 10;
        int n = nt * 16 + (l & 15);
        int kk = s * 32 + ((l >> 4) & 3) * 8 + j;
        Wo3f[idx] = f2b(n < 24 ? Wo3[kk * 24 + n] : 0.f);
    }
}

// ---------------- P1: x0 + u1/u2 (message-MLP layer-1 factorization) ----------------
// u1[b,n,k,h] = x0[b,n]·W1[k][0:24,h]  (sender);  u2 = x0·W1[k][24:48,h]+b1 (receiver)
__global__ void compute_u(const float* __restrict__ data, const float* __restrict__ act,
                          const float* __restrict__ Wm1, const float* __restrict__ bm1,
                          float* __restrict__ x0, u16* __restrict__ u1, u16* __restrict__ u2) {
    int r0 = blockIdx.x * 16;
    __shared__ float xs[16][24];
    int tid = threadIdx.x;
    for (int idx = tid; idx < 16 * 24; idx += 256) {
        int rr = idx / 24, d = idx % 24;
        int r = r0 + rr;
        float v = (d < 16) ? data[(r * 2 + 0) * 16 + d]       // t=0 only (output keeps t=0)
                           : act[(r * 2 + 0) * 8 + (d - 16)];
        xs[rr][d] = v;
        x0[r * 24 + d] = v;
    }
    __syncthreads();
    int h = tid;
    float acc[4][16];
#pragma unroll
    for (int q = 0; q < 4; q++)
#pragma unroll
        for (int rr = 0; rr < 16; rr++) acc[q][rr] = 0.f;
#pragma unroll
    for (int d = 0; d < 24; d++) {
        float w10 = Wm1[(0 * 48 + d) * 256 + h];
        float w11 = Wm1[(1 * 48 + d) * 256 + h];
        float w20 = Wm1[(0 * 48 + 24 + d) * 256 + h];
        float w21 = Wm1[(1 * 48 + 24 + d) * 256 + h];
#pragma unroll
        for (int rr = 0; rr < 16; rr++) {
            float x = xs[rr][d];
            acc[0][rr] += x * w10;
            acc[1][rr] += x * w11;
            acc[2][rr] += x * w20;
            acc[3][rr] += x * w21;
        }
    }
    float bb0 = bm1[h], bb1 = bm1[256 + h];
#pragma unroll
    for (int rr = 0; rr < 16; rr++) {
        int r = r0 + rr;
        u1[(r * 2 + 0) * 256 + h] = f2b(acc[0][rr]);
        u1[(r * 2 + 1) * 256 + h] = f2b(acc[1][rr]);
        u2[(r * 2 + 0) * 256 + h] = f2b(acc[2][rr] + bb0);
        u2[(r * 2 + 1) * 256 + h] = f2b(acc[3][rr] + bb1);
    }
}

// ---------------- K3: edge MLP layer-2 + weighted aggregate ----------------
// block = (b,i). A = relu(u1[b,j,k]+u2[b,i,k]) staged in LDS in A-fragment order
// (conflict-free b128); B fragments loaded global->reg from W2f (L2-hit, coalesced).
// No barriers inside the 8-step MFMA loop.
__global__ __launch_bounds__(256, 3) void edge_kernel(
    const u16* __restrict__ u1, const u16* __restrict__ u2, const float* __restrict__ edges,
    const u16* __restrict__ W2f, const float* __restrict__ bm2, float* __restrict__ agg) {
    int blk = blockIdx.x;
    int b = blk >> 6, i = blk & 63;
    __shared__ __align__(16) u16 Af[2048 * 8];    // [s<8][rt<4][lane][8] = 32 KB
    __shared__ float agg_s[256];                  // wave-private column ranges
    __shared__ float w_s[64];
    __shared__ float b2_s[256];
    int tid = threadIdx.x;
    int lane = tid & 63, wave = tid >> 6;
    agg_s[tid] = 0.f;
    const int colBase = wave * 64;
    const int lhi = lane >> 4;

    for (int k = 0; k < 2; k++) {
        __syncthreads();                 // all waves done with Af/w_s/b2_s of prev k
        if (tid < 64) {
            int j = tid;
            float w = 0.f;
            if (j != i) {
                int jj = j - (j > i ? 1 : 0);
                w = edges[(b * 4032 + i * 63 + jj) * 2 + k];
            }
            w_s[j] = w;
        }
        b2_s[tid] = bm2[k * 256 + tid];
        // stage A in fragment order: entry fi=(frag,lane_f) holds 8 u16
        const u16* u1b = u1 + ((size_t)(b * 128 + k)) * 256;   // + j*512 per row
        const u16* u2row = u2 + ((size_t)(b * 128 + 2 * i + k)) * 256;
#pragma unroll
        for (int it = 0; it < 8; it++) {
            int fi = tid + 256 * it;                // 0..2047
            int lane_f = fi & 63, frag = fi >> 6;   // frag = s*4+rt
            int s = frag >> 2, rt = frag & 3;
            int j = rt * 16 + (lane_f & 15);
            int c0 = s * 32 + (lane_f >> 4) * 8;
            uint4 v1 = *(const uint4*)(u1b + j * 512 + c0);
            uint4 v2 = *(const uint4*)(u2row + c0);
            const u16* s1 = (const u16*)&v1;
            const u16* s2 = (const u16*)&v2;
            u16 o[8];
#pragma unroll
            for (int q = 0; q < 8; q++)
                o[q] = f2b(fmaxf(b2f(s1[q]) + b2f(s2[q]), 0.f));
            *(uint4*)(&Af[fi * 8]) = *(const uint4*)o;
        }
        __syncthreads();

        floatx4 acc[4][4];
#pragma unroll
        for (int rt = 0; rt < 4; rt++)
#pragma unroll
            for (int ct = 0; ct < 4; ct++)
#pragma unroll
                for (int q = 0; q < 4; q++) acc[rt][ct][q] = 0.f;

#pragma unroll
        for (int step = 0; step < 8; step++) {
            const u16* Wk = W2f + ((size_t)((k * 8 + step) * 16 + wave * 4)) * 512;
            bf16x8 bfr[4], af[4];
#pragma unroll
            for (int ct = 0; ct < 4; ct++)
                bfr[ct] = *(const bf16x8*)(Wk + ct * 512 + lane * 8);
#pragma unroll
            for (int rt = 0; rt < 4; rt++)
                af[rt] = *(const bf16x8*)(&Af[((step * 4 + rt) * 64 + lane) * 8]);
#pragma unroll
            for (int rt = 0; rt < 4; rt++)
#pragma unroll
                for (int ct = 0; ct < 4; ct++)
                    acc[rt][ct] = __builtin_amdgcn_mfma_f32_16x16x32_bf16(
                        af[rt], bfr[ct], acc[rt][ct], 0, 0, 0);
        }
        // epilogue: relu(C+b2)*w, reduce over rows (C: col=lane&15, row=quad*4+reg)
#pragma unroll
        for (int ct = 0; ct < 4; ct++) {
            int col = colBase + ct * 16 + (lane & 15);
            float bb = b2_s[col];
            float p = 0.f;
#pragma unroll
            for (int rt = 0; rt < 4; rt++)
#pragma unroll
                for (int reg = 0; reg < 4; reg++) {
                    int row = rt * 16 + lhi * 4 + reg;
                    p += fmaxf(acc[rt][ct][reg] + bb, 0.f) * w_s[row];
                }
            p += __shfl_xor(p, 16, 64);
            p += __shfl_xor(p, 32, 64);
            if (lhi == 0) agg_s[col] += p;   // wave-private cols: no race
        }
    }
    // tid reads its own wave's columns: no barrier needed
    agg[(size_t)blk * 256 + tid] = agg_s[tid];
}

// ---------------- K4: out-MLP (280->256->256->24) + residual + q, one block per b ----------------
__global__ void out_mlp(const float* __restrict__ x0, const float* __restrict__ agg,
                        const u16* __restrict__ Wo1f, const u16* __restrict__ Wo2f,
                        const u16* __restrict__ Wo3f,
                        const float* __restrict__ bo1, const float* __restrict__ bo2,
                        const float* __restrict__ bo3,
                        const float* __restrict__ Wq2, const float* __restrict__ bq2,
                        const float* __restrict__ Wq3, const float* __restrict__ bq3,
                        float* __restrict__ out) {
    int b = blockIdx.x;
    int tid = threadIdx.x;
    int lane = tid & 63, wave = tid >> 6;
    const int colBase = wave * 64;
    const int lhi = lane >> 4;
    __shared__ __align__(16) u16 A1f[2304 * 8];   // [s<9][rt<4][lane][8] = 36 KB
    __shared__ __align__(16) u16 A2f[2048 * 8];   // h1 frags, 32 KB
    __shared__ __align__(16) u16 h2f[2048 * 8];   // h2 frags, 32 KB
    __shared__ float qs[4];

    // stage aug = [x0(24) | agg(256) | pad(8)] in A-fragment order
#pragma unroll
    for (int it = 0; it < 9; it++) {
        int fi = tid + 256 * it;                  // 0..2303
        int lane_f = fi & 63, frag = fi >> 6;
        int s = frag >> 2, rt = frag & 3;
        int m = rt * 16 + (lane_f & 15);          // node row 0..63
        int c0 = s * 32 + (lane_f >> 4) * 8;
        float vals[8];
        if (c0 < 24) {
            const float4* xr = (const float4*)(x0 + (b * 64 + m) * 24 + c0);
            float4 a = xr[0], c = xr[1];
            vals[0] = a.x; vals[1] = a.y; vals[2] = a.z; vals[3] = a.w;
            vals[4] = c.x; vals[5] = c.y; vals[6] = c.z; vals[7] = c.w;
        } else if (c0 < 280) {
            const float4* ar = (const float4*)(agg + ((size_t)(b * 64 + m)) * 256 + (c0 - 24));
            float4 a = ar[0], c = ar[1];
            vals[0] = a.x; vals[1] = a.y; vals[2] = a.z; vals[3] = a.w;
            vals[4] = c.x; vals[5] = c.y; vals[6] = c.z; vals[7] = c.w;
        } else {
#pragma unroll
            for (int q = 0; q < 8; q++) vals[q] = 0.f;
        }
        u16 o[8];
#pragma unroll
        for (int q = 0; q < 8; q++) o[q] = f2b(vals[q]);
        *(uint4*)(&A1f[fi * 8]) = *(const uint4*)o;
    }
    __syncthreads();

    // layer 1: M=64, N=256, K=288 (9 steps)
    floatx4 acc[4][4];
#pragma unroll
    for (int rt = 0; rt < 4; rt++)
#pragma unroll
        for (int ct = 0; ct < 4; ct++)
#pragma unroll
            for (int q = 0; q < 4; q++) acc[rt][ct][q] = 0.f;
#pragma unroll
    for (int step = 0; step < 9; step++) {
        const u16* Wk = Wo1f + ((size_t)(step * 16 + wave * 4)) * 512;
        bf16x8 bfr[4], af[4];
#pragma unroll
        for (int ct = 0; ct < 4; ct++) bfr[ct] = *(const bf16x8*)(Wk + ct * 512 + lane * 8);
#pragma unroll
        for (int rt = 0; rt < 4; rt++) af[rt] = *(const bf16x8*)(&A1f[((step * 4 + rt) * 64 + lane) * 8]);
#pragma unroll
        for (int rt = 0; rt < 4; rt++)
#pragma unroll
            for (int ct = 0; ct < 4; ct++)
                acc[rt][ct] = __builtin_amdgcn_mfma_f32_16x16x32_bf16(af[rt], bfr[ct], acc[rt][ct], 0, 0, 0);
    }
    // h1 = relu(C+bo1) -> A2f (fragment order, scalar u16 writes)
#pragma unroll
    for (int ct = 0; ct < 4; ct++) {
        int col = colBase + ct * 16 + (lane & 15);
        float bb = bo1[col];
        int s2 = col >> 5, jj = col & 7, lf_hi = ((col >> 3) & 3) << 4;
#pragma unroll
        for (int rt = 0; rt < 4; rt++)
#pragma unroll
            for (int reg = 0; reg < 4; reg++) {
                int row = rt * 16 + lhi * 4 + reg;
                int lane_f = (row & 15) | lf_hi;
                A2f[((s2 * 4 + rt) * 64 + lane_f) * 8 + jj] =
                    f2b(fmaxf(acc[rt][ct][reg] + bb, 0.f));
            }
    }
    __syncthreads();

    // layer 2: M=64, N=256, K=256 (8 steps)
#pragma unroll
    for (int rt = 0; rt < 4; rt++)
#pragma unroll
        for (int ct = 0; ct < 4; ct++)
#pragma unroll
            for (int q = 0; q < 4; q++) acc[rt][ct][q] = 0.f;
#pragma unroll
    for (int step = 0; step < 8; step++) {
        const u16* Wk = Wo2f + ((size_t)(step * 16 + wave * 4)) * 512;
        bf16x8 bfr[4], af[4];
#pragma unroll
        for (int ct = 0; ct < 4; ct++) bfr[ct] = *(const bf16x8*)(Wk + ct * 512 + lane * 8);
#pragma unroll
        for (int rt = 0; rt < 4; rt++) af[rt] = *(const bf16x8*)(&A2f[((step * 4 + rt) * 64 + lane) * 8]);
#pragma unroll
        for (int rt = 0; rt < 4; rt++)
#pragma unroll
            for (int ct = 0; ct < 4; ct++)
                acc[rt][ct] = __builtin_amdgcn_mfma_f32_16x16x32_bf16(af[rt], bfr[ct], acc[rt][ct], 0, 0, 0);
    }
    // h2 = relu(C+bo2) -> h2f fragments
#pragma unroll
    for (int ct = 0; ct < 4; ct++) {
        int col = colBase + ct * 16 + (lane & 15);
        float bb = bo2[col];
        int s2 = col >> 5, jj = col & 7, lf_hi = ((col >> 3) & 3) << 4;
#pragma unroll
        for (int rt = 0; rt < 4; rt++)
#pragma unroll
            for (int reg = 0; reg < 4; reg++) {
                int row = rt * 16 + lhi * 4 + reg;
                int lane_f = (row & 15) | lf_hi;
                h2f[((s2 * 4 + rt) * 64 + lane_f) * 8 + jj] =
                    f2b(fmaxf(acc[rt][ct][reg] + bb, 0.f));
            }
    }
    __syncthreads();

    // layer 3: M=64, N=32(24), K=256; wave w owns row-tile rt=w, ct 0..1
    floatx4 acc3[2];
#pragma unroll
    for (int ct = 0; ct < 2; ct++)
#pragma unroll
        for (int q = 0; q < 4; q++) acc3[ct][q] = 0.f;
#pragma unroll
    for (int step = 0; step < 8; step++) {
        bf16x8 af = *(const bf16x8*)(&h2f[((step * 4 + wave) * 64 + lane) * 8]);
#pragma unroll
        for (int ct = 0; ct < 2; ct++) {
            bf16x8 bfr = *(const bf16x8*)(Wo3f + ((size_t)(step * 2 + ct)) * 512 + lane * 8);
            acc3[ct] = __builtin_amdgcn_mfma_f32_16x16x32_bf16(af, bfr, acc3[ct], 0, 0, 0);
        }
    }
    // epilogue: residual + q2 dot + reduce to out[b]
    float pr[4];
#pragma unroll
    for (int reg = 0; reg < 4; reg++) {
        float p = 0.f;
#pragma unroll
        for (int ct = 0; ct < 2; ct++) {
            int col = ct * 16 + (lane & 15);
            if (col < 24) {
                int row = wave * 16 + lhi * 4 + reg;
                float val = acc3[ct][reg] + bo3[col] + x0[(b * 64 + row) * 24 + col];
                p += val * Wq2[col];
            }
        }
        pr[reg] = p;
    }
#pragma unroll
    for (int off = 1; off <= 8; off <<= 1)
#pragma unroll
        for (int reg = 0; reg < 4; reg++) pr[reg] += __shfl_xor(pr[reg], off, 64);
    float contrib = 0.f;
    if ((lane & 15) == 0) {
#pragma unroll
        for (int reg = 0; reg < 4; reg++) {
            int row = wave * 16 + lhi * 4 + reg;
            contrib += (pr[reg] + bq2[0]) * Wq3[row];
        }
    }
    contrib += __shfl_xor(contrib, 16, 64);
    contrib += __shfl_xor(contrib, 32, 64);
    if (lane == 0) qs[wave] = contrib;
    __syncthreads();
    if (tid == 0) out[b] = bq3[0] + qs[0] + qs[1] + qs[2] + qs[3];
}

extern "C" void kernel_launch(void* const* d_in, const int* in_sizes, int n_in,
                              void* d_out, int out_size, void* d_ws, size_t ws_size,
                              hipStream_t stream) {
    const float* data = (const float*)d_in[0];
    const float* act  = (const float*)d_in[1];
    const float* edges = (const float*)d_in[2];
    // d_in[3] rel_rec, d_in[4] rel_send, d_in[5] prediction_steps: structure hardcoded (steps=1)
    const float* Wm1 = (const float*)d_in[6];
    const float* bm1 = (const float*)d_in[7];
    const float* Wm2 = (const float*)d_in[8];
    const float* bm2 = (const float*)d_in[9];
    const float* Wo1 = (const float*)d_in[10];
    const float* bo1 = (const float*)d_in[11];
    const float* Wo2 = (const float*)d_in[12];
    const float* bo2 = (const float*)d_in[13];
    const float* Wo3 = (const float*)d_in[14];
    const float* bo3 = (const float*)d_in[15];
    const float* Wq2 = (const float*)d_in[16];
    const float* bq2 = (const float*)d_in[17];
    const float* Wq3 = (const float*)d_in[18];
    const float* bq3 = (const float*)d_in[19];
    float* out = (float*)d_out;

    char* ws = (char*)d_ws;
    size_t off = 0;
    auto carve = [&](size_t bytes) -> void* {
        void* p = ws + off;
        off += (bytes + 255) & ~(size_t)255;
        return p;
    };
    u16*   u1   = (u16*)carve((size_t)64 * 64 * 2 * 256 * 2);
    u16*   u2   = (u16*)carve((size_t)64 * 64 * 2 * 256 * 2);
    float* x0   = (float*)carve((size_t)64 * 64 * 24 * 4);
    float* agg  = (float*)carve((size_t)64 * 64 * 256 * 4);
    u16*   W2f  = (u16*)carve((size_t)2 * 8 * 16 * 64 * 8 * 2);
    u16*   Wo1f = (u16*)carve((size_t)9 * 16 * 64 * 8 * 2);
    u16*   Wo2f = (u16*)carve((size_t)8 * 16 * 64 * 8 * 2);
    u16*   Wo3f = (u16*)carve((size_t)8 * 2 * 64 * 8 * 2);

    prep_weights<<<dim3(512), dim3(256), 0, stream>>>(Wm2, Wo1, Wo2, Wo3, W2f, Wo1f, Wo2f, Wo3f);
    compute_u<<<dim3(256), dim3(256), 0, stream>>>(data, act, Wm1, bm1, x0, u1, u2);
    edge_kernel<<<dim3(4096), dim3(256), 0, stream>>>(u1, u2, edges, W2f, bm2, agg);
    out_mlp<<<dim3(64), dim3(256), 0, stream>>>(x0, agg, Wo1f, Wo2f, Wo3f, bo1, bo2, bo3,
                                                Wq2, bq2, Wq3, bq3, out);
}